// Round 22
// baseline (37.714 us; speedup 1.0000x reference)
//
#include <hip/hip_runtime.h>

#ifndef __has_builtin
#define __has_builtin(x) 0
#endif

#if __has_builtin(__builtin_amdgcn_sdot4)
#define DOT4(a, b, c) __builtin_amdgcn_sdot4((a), (b), (c), false)
#else
__device__ __forceinline__ int dot4_sw(int a, int b, int c) {
#pragma unroll
    for (int k = 0; k < 4; ++k)
        c += (int)(signed char)((a >> (8 * k)) & 0xff) *
             (int)(signed char)((b >> (8 * k)) & 0xff);
    return c;
}
#define DOT4(a, b, c) dot4_sw((a), (b), (c))
#endif

#if __has_builtin(__builtin_amdgcn_sched_barrier)
#define SCHED_FENCE() __builtin_amdgcn_sched_barrier(0)
#else
#define SCHED_FENCE() asm volatile("" ::: "memory")
#endif

typedef float vfloat4 __attribute__((ext_vector_type(4)));

constexpr int CH   = 256;
constexpr int NPIX = 1024;   // 32*32
constexpr float BN_EPS = 1e-5f;
constexpr int THROTTLE_LDS = 81920;   // 2 x 80KB = 160KiB -> 2 blocks/CU

// R15 structure (best 30.4us) + REAL occupancy throttle via DYNAMIC shared
// memory (80KB requested at launch -> dispatch-packet group segment, cannot
// be compiler-elided; R21's static ballast was folded away, LDS_Block_Size=0).
// 2 blocks/CU -> grid 2048 runs in 4 residency rounds; within a round each
// XCD's 64 resident blocks work ONE image-pair = 2MB live < 4MB L2 -> the
// conv->shortcut reuse distance finally fits L2. Tests the FETCH=33MB theory.
__global__ __launch_bounds__(256, 2)
void bconv(const float* __restrict__ x,
           const float* __restrict__ wgt,
           const float* __restrict__ gamma,
           const float* __restrict__ beta,
           const float* __restrict__ rmean,
           const float* __restrict__ rvar,
           float* __restrict__ out) {
    extern __shared__ char dyn_lds[];
    const int tid = threadIdx.x;
    // data-dependent guard (never true for N(0,0.01) weights; unfoldable):
    // forces dyn_lds to be "used" so nothing strips the allocation.
    if (wgt[0] == 1e30f) ((volatile char*)dyn_lds)[tid] = 1;

    // bijective XCD-chunked swizzle (nwg=2048, q=256): co-locates each
    // n-pair's 64 group-blocks on one XCD -> shortcut re-reads hit L2.
    const int bid = blockIdx.x;
    const int swz = (bid & 7) * 256 + (bid >> 3);
    const int n0  = (swz >> 6) * 2;
    const int g   = swz & 63;

    const int pix0 = tid * 4;
    const int row  = pix0 >> 5;
    const int col0 = pix0 & 31;
    const float* xnA = x + n0 * CH * NPIX;
    const float* xnB = xnA + CH * NPIX;
    float* onA = out + n0 * CH * NPIX;
    float* onB = onA + CH * NPIX;

    // ---- phase 1: issue ALL image-A loads (12 row + 4 shortcut) ----
    vfloat4 xvA[3][4];
#pragma unroll
    for (int kh = 0; kh < 3; ++kh) {
        const int rsc = min(max(row + 2 * kh - 2, 0), 31);
        const float* rp = xnA + g * 4 * NPIX + rsc * 32 + col0;
#pragma unroll
        for (int ci = 0; ci < 4; ++ci)
            xvA[kh][ci] = *(const vfloat4*)(rp + ci * NPIX);
    }
    vfloat4 scA[4];
#pragma unroll
    for (int c2 = 0; c2 < 4; ++c2)
        scA[c2] = *(const vfloat4*)(xnA + (c2 * 64 + g) * NPIX + pix0);
    SCHED_FENCE();   // A loads may not sink below this point

    // ---- weights: SALU sign-pack (uniform int loads -> SGPRs; exact) ----
    const int* wb = (const int*)(wgt + g * 144);  // [c2][ci][tap] as ints
    int wq[4][9];
#pragma unroll
    for (int c2 = 0; c2 < 4; ++c2)
#pragma unroll
        for (int t = 0; t < 9; ++t) {
            int pk = 0;
#pragma unroll
            for (int ci = 0; ci < 4; ++ci) {
                const int b = wb[c2 * 36 + ci * 9 + t];
                const int s = ((b & 0x7fffffff) == 0) ? 0 : ((b < 0) ? -1 : 1);
                pk |= (s & 0xff) << (8 * ci);
            }
            wq[c2][t] = pk;
        }

    // ---- BN consts (uniform; exact numpy op order, no FMA) ----
    float inv[4], bias[4];
#pragma unroll
    for (int ci = 0; ci < 4; ++ci) {
        const int c = g * 4 + ci;
        float r  = __fdiv_rn(1.0f, __fsqrt_rn(__fadd_rn(rvar[c], BN_EPS)));
        inv[ci]  = __fmul_rn(gamma[c], r);
        bias[ci] = __fsub_rn(beta[c], __fmul_rn(rmean[c], inv[ci]));
    }

    auto pack = [&](const vfloat4 xv[3][4], int pkc[3][4]) {
#pragma unroll
        for (int kh = 0; kh < 3; ++kh) {
            const bool ok = (unsigned)(row + 2 * kh - 2) < 32u;
#pragma unroll
            for (int p = 0; p < 4; ++p) {
                int v = 0;
#pragma unroll
                for (int ci = 0; ci < 4; ++ci) {
                    float h = __fadd_rn(__fmul_rn(xv[kh][ci][p], inv[ci]), bias[ci]);
                    int s = (h > 0.f) ? 1 : ((h < 0.f) ? -1 : 0);
                    v |= (s & 0xff) << (8 * ci);
                }
                pkc[kh][p] = ok ? v : 0;
            }
        }
    };

    const bool le = (col0 == 0), re = (col0 == 28);
    auto compute_store = [&](const int pkc[3][4], const vfloat4 sc[4], float* on) {
        int a[3][8];
#pragma unroll
        for (int kh = 0; kh < 3; ++kh) {
            int l2 = __shfl_up(pkc[kh][2], 1);
            int l3 = __shfl_up(pkc[kh][3], 1);
            int r0 = __shfl_down(pkc[kh][0], 1);
            int r1 = __shfl_down(pkc[kh][1], 1);
            a[kh][0] = le ? 0 : l2;
            a[kh][1] = le ? 0 : l3;
            a[kh][2] = pkc[kh][0]; a[kh][3] = pkc[kh][1];
            a[kh][4] = pkc[kh][2]; a[kh][5] = pkc[kh][3];
            a[kh][6] = re ? 0 : r0;
            a[kh][7] = re ? 0 : r1;
        }
#pragma unroll
        for (int c2 = 0; c2 < 4; ++c2) {
            vfloat4 o;
#pragma unroll
            for (int p = 0; p < 4; ++p) {
                int acc = 0;
#pragma unroll
                for (int kh = 0; kh < 3; ++kh)
#pragma unroll
                    for (int kw = 0; kw < 3; ++kw)
                        acc = DOT4(a[kh][p + 2 * kw], wq[c2][kh * 3 + kw], acc);
                o[p] = __fadd_rn((float)acc, sc[c2][p]);
            }
            // out is never re-read: nontemporal keeps L2/L3 for x
            __builtin_nontemporal_store(o, (vfloat4*)(on + (c2 * 64 + g) * NPIX + pix0));
        }
    };

    // ---- phase 2: pack A (fine-grained vmcnt waits on xvA only) ----
    int pkcA[3][4];
    pack(xvA, pkcA);

    // ---- phase 3: issue ALL image-B row loads, pinned above compute-A ----
    vfloat4 xvB[3][4];
#pragma unroll
    for (int kh = 0; kh < 3; ++kh) {
        const int rsc = min(max(row + 2 * kh - 2, 0), 31);
        const float* rp = xnB + g * 4 * NPIX + rsc * 32 + col0;
#pragma unroll
        for (int ci = 0; ci < 4; ++ci)
            xvB[kh][ci] = *(const vfloat4*)(rp + ci * NPIX);
    }
    SCHED_FENCE();   // B loads may not sink below; compute-A may not hoist above

    // ---- phase 4: compute + store A (B loads in flight underneath) ----
    compute_store(pkcA, scA, onA);

    // ---- phase 5: issue B shortcut loads (L2-resident), then pack B ----
    vfloat4 scB[4];
#pragma unroll
    for (int c2 = 0; c2 < 4; ++c2)
        scB[c2] = *(const vfloat4*)(xnB + (c2 * 64 + g) * NPIX + pix0);
    SCHED_FENCE();   // scB issues before the B dot4 chain

    int pkcB[3][4];
    pack(xvB, pkcB);
    compute_store(pkcB, scB, onB);
}

extern "C" void kernel_launch(void* const* d_in, const int* in_sizes, int n_in,
                              void* d_out, int out_size, void* d_ws, size_t ws_size,
                              hipStream_t stream) {
    const float* x     = (const float*)d_in[0];
    const float* wgt   = (const float*)d_in[1];
    const float* gamma = (const float*)d_in[2];
    const float* beta  = (const float*)d_in[3];
    const float* rmean = (const float*)d_in[4];
    const float* rvar  = (const float*)d_in[5];
    float* out = (float*)d_out;

    const int N = in_sizes[0] / (CH * NPIX);  // 64
    // dynamic shared memory request forces the 80KB group segment (2 blk/CU)
    bconv<<<(N / 2) * 64, 256, THROTTLE_LDS, stream>>>(x, wgt, gamma, beta,
                                                       rmean, rvar, out);
}

// Round 23
// 30.478 us; speedup vs baseline: 1.2374x; 1.2374x over previous
//
#include <hip/hip_runtime.h>

#ifndef __has_builtin
#define __has_builtin(x) 0
#endif

#if __has_builtin(__builtin_amdgcn_sdot4)
#define DOT4(a, b, c) __builtin_amdgcn_sdot4((a), (b), (c), false)
#else
__device__ __forceinline__ int dot4_sw(int a, int b, int c) {
#pragma unroll
    for (int k = 0; k < 4; ++k)
        c += (int)(signed char)((a >> (8 * k)) & 0xff) *
             (int)(signed char)((b >> (8 * k)) & 0xff);
    return c;
}
#define DOT4(a, b, c) dot4_sw((a), (b), (c))
#endif

#if __has_builtin(__builtin_amdgcn_sched_barrier)
#define SCHED_FENCE() __builtin_amdgcn_sched_barrier(0)
#else
#define SCHED_FENCE() asm volatile("" ::: "memory")
#endif

typedef float vfloat4 __attribute__((ext_vector_type(4)));

constexpr int CH   = 256;
constexpr int NPIX = 1024;   // 32*32
constexpr float BN_EPS = 1e-5f;

// FINAL (best config, measured 30.6/30.4us): zero-s_barrier, zero-LDS,
// 2 images per block, sched_barrier(0)-pinned load schedule, SALU weight
// sign-pack, lane-shuffle halo, XCD-chunked bijective swizzle, NT stores.
// Session evidence: time = (33MB fetch + 64MiB write) / ~3.2 TB/s across
// 10 structural variants; traffic is irreducible (fetch = L3 eviction of x
// by the write stream; write mandatory). This is the practical plateau.
__global__ __launch_bounds__(256, 4)
void bconv(const float* __restrict__ x,
           const float* __restrict__ wgt,
           const float* __restrict__ gamma,
           const float* __restrict__ beta,
           const float* __restrict__ rmean,
           const float* __restrict__ rvar,
           float* __restrict__ out) {
    const int tid = threadIdx.x;
    // bijective XCD-chunked swizzle (nwg=2048, q=256): co-locates each
    // n-pair's 64 group-blocks on one XCD -> shortcut re-reads hit L2.
    const int bid = blockIdx.x;
    const int swz = (bid & 7) * 256 + (bid >> 3);
    const int n0  = (swz >> 6) * 2;
    const int g   = swz & 63;

    const int pix0 = tid * 4;
    const int row  = pix0 >> 5;
    const int col0 = pix0 & 31;
    const float* xnA = x + n0 * CH * NPIX;
    const float* xnB = xnA + CH * NPIX;
    float* onA = out + n0 * CH * NPIX;
    float* onB = onA + CH * NPIX;

    // ---- phase 1: issue ALL image-A loads (12 row + 4 shortcut) ----
    vfloat4 xvA[3][4];
#pragma unroll
    for (int kh = 0; kh < 3; ++kh) {
        const int rsc = min(max(row + 2 * kh - 2, 0), 31);
        const float* rp = xnA + g * 4 * NPIX + rsc * 32 + col0;
#pragma unroll
        for (int ci = 0; ci < 4; ++ci)
            xvA[kh][ci] = *(const vfloat4*)(rp + ci * NPIX);
    }
    vfloat4 scA[4];
#pragma unroll
    for (int c2 = 0; c2 < 4; ++c2)
        scA[c2] = *(const vfloat4*)(xnA + (c2 * 64 + g) * NPIX + pix0);
    SCHED_FENCE();   // A loads may not sink below this point

    // ---- weights: SALU sign-pack (uniform int loads -> SGPRs; exact) ----
    const int* wb = (const int*)(wgt + g * 144);  // [c2][ci][tap] as ints
    int wq[4][9];
#pragma unroll
    for (int c2 = 0; c2 < 4; ++c2)
#pragma unroll
        for (int t = 0; t < 9; ++t) {
            int pk = 0;
#pragma unroll
            for (int ci = 0; ci < 4; ++ci) {
                const int b = wb[c2 * 36 + ci * 9 + t];
                const int s = ((b & 0x7fffffff) == 0) ? 0 : ((b < 0) ? -1 : 1);
                pk |= (s & 0xff) << (8 * ci);
            }
            wq[c2][t] = pk;
        }

    // ---- BN consts (uniform; exact numpy op order, no FMA) ----
    float inv[4], bias[4];
#pragma unroll
    for (int ci = 0; ci < 4; ++ci) {
        const int c = g * 4 + ci;
        float r  = __fdiv_rn(1.0f, __fsqrt_rn(__fadd_rn(rvar[c], BN_EPS)));
        inv[ci]  = __fmul_rn(gamma[c], r);
        bias[ci] = __fsub_rn(beta[c], __fmul_rn(rmean[c], inv[ci]));
    }

    auto pack = [&](const vfloat4 xv[3][4], int pkc[3][4]) {
#pragma unroll
        for (int kh = 0; kh < 3; ++kh) {
            const bool ok = (unsigned)(row + 2 * kh - 2) < 32u;
#pragma unroll
            for (int p = 0; p < 4; ++p) {
                int v = 0;
#pragma unroll
                for (int ci = 0; ci < 4; ++ci) {
                    float h = __fadd_rn(__fmul_rn(xv[kh][ci][p], inv[ci]), bias[ci]);
                    int s = (h > 0.f) ? 1 : ((h < 0.f) ? -1 : 0);
                    v |= (s & 0xff) << (8 * ci);
                }
                pkc[kh][p] = ok ? v : 0;
            }
        }
    };

    const bool le = (col0 == 0), re = (col0 == 28);
    auto compute_store = [&](const int pkc[3][4], const vfloat4 sc[4], float* on) {
        int a[3][8];
#pragma unroll
        for (int kh = 0; kh < 3; ++kh) {
            int l2 = __shfl_up(pkc[kh][2], 1);
            int l3 = __shfl_up(pkc[kh][3], 1);
            int r0 = __shfl_down(pkc[kh][0], 1);
            int r1 = __shfl_down(pkc[kh][1], 1);
            a[kh][0] = le ? 0 : l2;
            a[kh][1] = le ? 0 : l3;
            a[kh][2] = pkc[kh][0]; a[kh][3] = pkc[kh][1];
            a[kh][4] = pkc[kh][2]; a[kh][5] = pkc[kh][3];
            a[kh][6] = re ? 0 : r0;
            a[kh][7] = re ? 0 : r1;
        }
#pragma unroll
        for (int c2 = 0; c2 < 4; ++c2) {
            vfloat4 o;
#pragma unroll
            for (int p = 0; p < 4; ++p) {
                int acc = 0;
#pragma unroll
                for (int kh = 0; kh < 3; ++kh)
#pragma unroll
                    for (int kw = 0; kw < 3; ++kw)
                        acc = DOT4(a[kh][p + 2 * kw], wq[c2][kh * 3 + kw], acc);
                o[p] = __fadd_rn((float)acc, sc[c2][p]);
            }
            // out is never re-read: nontemporal keeps L2 for x
            __builtin_nontemporal_store(o, (vfloat4*)(on + (c2 * 64 + g) * NPIX + pix0));
        }
    };

    // ---- phase 2: pack A (fine-grained vmcnt waits on xvA only) ----
    int pkcA[3][4];
    pack(xvA, pkcA);

    // ---- phase 3: issue ALL image-B row loads, pinned above compute-A ----
    vfloat4 xvB[3][4];
#pragma unroll
    for (int kh = 0; kh < 3; ++kh) {
        const int rsc = min(max(row + 2 * kh - 2, 0), 31);
        const float* rp = xnB + g * 4 * NPIX + rsc * 32 + col0;
#pragma unroll
        for (int ci = 0; ci < 4; ++ci)
            xvB[kh][ci] = *(const vfloat4*)(rp + ci * NPIX);
    }
    SCHED_FENCE();   // B loads may not sink below; compute-A may not hoist above

    // ---- phase 4: compute + store A (B loads in flight underneath) ----
    compute_store(pkcA, scA, onA);

    // ---- phase 5: issue B shortcut loads (L2-resident), then pack B ----
    vfloat4 scB[4];
#pragma unroll
    for (int c2 = 0; c2 < 4; ++c2)
        scB[c2] = *(const vfloat4*)(xnB + (c2 * 64 + g) * NPIX + pix0);
    SCHED_FENCE();   // scB issues before the B dot4 chain

    int pkcB[3][4];
    pack(xvB, pkcB);
    compute_store(pkcB, scB, onB);
}

extern "C" void kernel_launch(void* const* d_in, const int* in_sizes, int n_in,
                              void* d_out, int out_size, void* d_ws, size_t ws_size,
                              hipStream_t stream) {
    const float* x     = (const float*)d_in[0];
    const float* wgt   = (const float*)d_in[1];
    const float* gamma = (const float*)d_in[2];
    const float* beta  = (const float*)d_in[3];
    const float* rmean = (const float*)d_in[4];
    const float* rvar  = (const float*)d_in[5];
    float* out = (float*)d_out;

    const int N = in_sizes[0] / (CH * NPIX);  // 64
    bconv<<<(N / 2) * 64, 256, 0, stream>>>(x, wgt, gamma, beta, rmean, rvar, out);
}